// Round 2
// baseline (185.315 us; speedup 1.0000x reference)
//
#include <hip/hip_runtime.h>
#include <stdint.h>
#include <stddef.h>

// ============================================================================
// SumSampler: bit-exact replication of the JAX reference sampler.
// R1: fused single-kernel version. One block per batch row (1024 thr, 2
// samples/thread); per-row histogram in LDS; p = logit - 0.1*log(counter)
// hoisted to LDS once per row. All sampling arithmetic is op-for-op identical
// to the R0 kernel that passed with absmax = 0.0.
//
// Locked-in facts from R0:
//   - JAX partitionable threefry: split -> {enc(0,0) carried, enc(0,1) sub};
//     random_bits[n] = o0 ^ o1 of enc_sub(0, n), n row-major over (B,S,10).
//   - f32 log = Eigen/Cephes plog, FMA at pmadd sites, unfused tail.
//   - d_out = float32, outputs concatenated [n1_samples | n2d | weights].
// ============================================================================

namespace {

constexpr int B = 512, S = 2048, D = 4, NC = 10;
constexpr int BS = B * S;                       // 1048576
constexpr size_t OUT1_OFF = (size_t)BS * D;     // 4194304
constexpr size_t OUT2_OFF = (size_t)BS * D * 2; // 8388608

// ---------------- constexpr Threefry2x32 (compile-time key derivation) ------
constexpr uint32_t crotl(uint32_t x, int d) { return (x << d) | (x >> (32 - d)); }
struct CU2 { uint32_t a, b; };
constexpr CU2 ctf(uint32_t k0, uint32_t k1, uint32_t c0, uint32_t c1) {
  uint32_t ks2 = k0 ^ k1 ^ 0x1BD11BDAu;
  uint32_t x0 = c0 + k0, x1 = c1 + k1;
  const int rots[8] = {13, 15, 26, 6, 17, 29, 16, 24};
  const uint32_t ks[3] = {k0, k1, ks2};
  for (int blk = 0; blk < 5; ++blk) {
    for (int j = 0; j < 4; ++j) {
      int r = rots[(blk & 1) * 4 + j];
      x0 += x1; x1 = crotl(x1, r); x1 ^= x0;
    }
    x0 += ks[(blk + 1) % 3];
    x1 += ks[(blk + 2) % 3] + (uint32_t)(blk + 1);
  }
  return CU2{x0, x1};
}

struct Keys { uint32_t kx[D]; uint32_t ky[D]; };
constexpr Keys make_keys() {
  Keys K{};
  uint32_t a = 0u, b = 42u;  // jax.random.key(42) -> (0, 42)
  for (int i = 0; i < D; ++i) {
    CU2 sub = ctf(a, b, 0u, 1u);  // split[1] = subkey (foldlike)
    CU2 nk  = ctf(a, b, 0u, 0u);  // split[0] = carried key
    K.kx[i] = sub.a; K.ky[i] = sub.b;
    a = nk.a; b = nk.b;
  }
  return K;
}
constexpr Keys KEYS = make_keys();

// ---------------- device Threefry2x32 ---------------------------------------
struct U2 { uint32_t a, b; };
__device__ __forceinline__ uint32_t rotl32(uint32_t x, int d) {
  return (x << d) | (x >> (32 - d));   // -> v_alignbit_b32
}
__device__ __forceinline__ U2 tf(uint32_t k0, uint32_t k1, uint32_t c0, uint32_t c1) {
  uint32_t ks2 = k0 ^ k1 ^ 0x1BD11BDAu;
  uint32_t x0 = c0 + k0, x1 = c1 + k1;
#define TF_RND(r) { x0 += x1; x1 = rotl32(x1, (r)); x1 ^= x0; }
  TF_RND(13) TF_RND(15) TF_RND(26) TF_RND(6)   x0 += k1;  x1 += ks2 + 1u;
  TF_RND(17) TF_RND(29) TF_RND(16) TF_RND(24)  x0 += ks2; x1 += k0 + 2u;
  TF_RND(13) TF_RND(15) TF_RND(26) TF_RND(6)   x0 += k0;  x1 += k1 + 3u;
  TF_RND(17) TF_RND(29) TF_RND(16) TF_RND(24)  x0 += k1;  x1 += ks2 + 4u;
  TF_RND(13) TF_RND(15) TF_RND(26) TF_RND(6)   x0 += ks2; x1 += k0 + 5u;
#undef TF_RND
  return U2{x0, x1};
}

// ---------------- f32 log: Eigen/Cephes plog, Variant-E (verified R0) -------
__device__ __forceinline__ float xla_logf(float a) {
  uint32_t bits = __float_as_uint(a);
  float e = (float)((int)(bits >> 23) - 126);                    // pfrexp exp
  float m = __uint_as_float((bits & 0x007fffffu) | 0x3f000000u); // [0.5, 1)
  bool mlt = m < 0.707106781186547524f;                          // SQRTHF
  float tmp = mlt ? m : 0.0f;
  float x = __fsub_rn(m, 1.0f);
  e = __fsub_rn(e, mlt ? 1.0f : 0.0f);
  x = __fadd_rn(x, tmp);
  float x2 = __fmul_rn(x, x);
  float x3 = __fmul_rn(x2, x);
  float y  = __fmaf_rn(7.0376836292e-2f,  x, -1.1514610310e-1f);
  float y1 = __fmaf_rn(-1.2420140846e-1f, x,  1.4249322787e-1f);
  float y2 = __fmaf_rn(2.0000714765e-1f,  x, -2.4999993993e-1f);
  y  = __fmaf_rn(y,  x,  1.1676998740e-1f);
  y1 = __fmaf_rn(y1, x, -1.6668057665e-1f);
  y2 = __fmaf_rn(y2, x,  3.3333331174e-1f);
  y  = __fmaf_rn(y, x3, y1);
  y  = __fmaf_rn(y, x3, y2);
  y  = __fmul_rn(y, x3);
  y1 = __fmul_rn(e, -2.12194440e-4f);
  tmp = __fmul_rn(x2, 0.5f);
  y = __fadd_rn(y, y1);
  x = __fsub_rn(x, tmp);
  y2 = __fmul_rn(e, 0.693359375f);
  x = __fadd_rn(x, y);
  x = __fadd_rn(x, y2);
  return x;
}

__device__ __forceinline__ float gumbel_from_bits(uint32_t bits) {
  float f = __fsub_rn(__uint_as_float((bits >> 9) | 0x3f800000u), 1.0f);
  float u = __fadd_rn(f, 1.17549435e-38f);  // == f unless f == 0 -> tiny
  float l1 = xla_logf(u);
  float l2 = xla_logf(-l1);
  return -l2;
}

// ---------------- fused kernel: sample + n2 digits + per-row weights --------
// One block per batch row. 1024 threads x 2 samples. hist: 10000 bins LDS.
__global__ __launch_bounds__(1024) void fused_kernel(
    const float* __restrict__ logits,   // [B, D, NC]
    const float* __restrict__ counters, // [D, NC]
    const int*   __restrict__ s_in,     // [B]
    float* __restrict__ out)            // concat(n1_samples, n2d, weights)
{
  __shared__ int hist[10000];           // 40 KB
  __shared__ float s_p[D * NC];         // logit - 0.1*log(counter), this row
  const int t = threadIdx.x;
  const int b = blockIdx.x;

  for (int i = t; i < 10000; i += 1024) hist[i] = 0;
  if (t < D * NC) {
    // identical ops to R0: load logit, fsub the 0.1*log(counter) term
    s_p[t] = __fsub_rn(logits[b * D * NC + t],
                       __fmul_rn(0.1f, xla_logf(counters[t])));
  }
  __syncthreads();

  const int sval = s_in[b];             // wave-uniform (scalar)
  const int mx[D] = {sval / 1000, (sval / 100) % 10, (sval / 10) % 10, sval % 10};

  int vals[2];
#pragma unroll
  for (int k = 0; k < 2; ++k) {
    const int sidx = t + k * 1024;
    const uint32_t n0 = (uint32_t)(b * S + sidx) * (uint32_t)NC;
    int con = 0;
    int dg[D];
#pragma unroll
    for (int i = 0; i < D; ++i) {
      const uint32_t kx = KEYS.kx[i], ky = KEYS.ky[i];
      const int mxi = mx[i];
      float best = -__builtin_inff();
      int bi = 0;
#pragma unroll
      for (int c = 0; c < NC; ++c) {
        U2 r = tf(kx, ky, 0u, n0 + (uint32_t)c);
        float g = gumbel_from_bits(r.a ^ r.b);
        float v = __fadd_rn(g, s_p[i * NC + c]);    // p precomputed per row
        bool allowed = (con != 0) || (c <= mxi);
        if (allowed && v > best) { best = v; bi = c; }  // first max wins
      }
      dg[i] = bi;
      con |= (bi != mxi);
    }

    const int n1v = dg[0] * 1000 + dg[1] * 100 + dg[2] * 10 + dg[3];
    vals[k] = n1v;
    atomicAdd(&hist[n1v], 1);

    const int n2 = sval - n1v;          // in [0, 10^D)
    const int q0 = n2 / 1000, q1 = (n2 / 100) % 10, q2 = (n2 / 10) % 10, q3 = n2 % 10;

    const size_t o = (size_t)(b * S + sidx) * D;
    *reinterpret_cast<float4*>(out + o) =
        make_float4((float)dg[0], (float)dg[1], (float)dg[2], (float)dg[3]);
    *reinterpret_cast<float4*>(out + OUT1_OFF + o) =
        make_float4((float)q0, (float)q1, (float)q2, (float)q3);
  }

  __syncthreads();
#pragma unroll
  for (int k = 0; k < 2; ++k) {
    const int sidx = t + k * 1024;
    out[OUT2_OFF + (size_t)b * S + sidx] = (float)hist[vals[k]];
  }
}

}  // namespace

extern "C" void kernel_launch(void* const* d_in, const int* in_sizes, int n_in,
                              void* d_out, int out_size, void* d_ws, size_t ws_size,
                              hipStream_t stream) {
  const float* logits   = (const float*)d_in[0];  // [512,4,10]
  const float* counters = (const float*)d_in[1];  // [4,10]
  const int*   s_in     = (const int*)d_in[2];    // [512]
  float* out = (float*)d_out;

  fused_kernel<<<B, 1024, 0, stream>>>(logits, counters, s_in, out);
}

// Round 4
// 180.327 us; speedup vs baseline: 1.0277x; 1.0277x over previous
//
#include <hip/hip_runtime.h>
#include <stdint.h>
#include <stddef.h>

// ============================================================================
// SumSampler: bit-exact replication of the JAX reference sampler.
// R4 == R3 resubmit (R3 bench died on infra, no data). Changes vs R2:
//   - ILP restructure: per digit, compute all 10 independent threefry streams
//     into a reg array FIRST, then the 10 gumbel chains + max scan. Attacks
//     the serial-dep-chain latency bound (R1 ran at ~30% of VALU issue floor).
//   - row-uniform p = logit - 0.1*log(counter) hoisted LDS -> readfirstlane
//     SGPRs; hot loop has zero memory ops.
//   - sample kernel writes n1v ints to d_ws; weights kernel reads 4MB ints
//     (not 16MB floats). Fallback template path if ws too small.
//   - per-digit work in template<int I> so threefry keys fold to literals.
// Locked-in (absmax=0.0 in R0/R2): partitionable threefry, Variant-E log,
// f32 outputs [n1_samples | n2d | weights].
// ============================================================================

namespace {

constexpr int B = 512, S = 2048, D = 4, NC = 10;
constexpr int BS = B * S;                       // 1048576
constexpr size_t OUT1_OFF = (size_t)BS * D;     // 4194304
constexpr size_t OUT2_OFF = (size_t)BS * D * 2; // 8388608

// ---------------- constexpr Threefry2x32 (compile-time key derivation) ------
constexpr uint32_t crotl(uint32_t x, int d) { return (x << d) | (x >> (32 - d)); }
struct CU2 { uint32_t a, b; };
constexpr CU2 ctf(uint32_t k0, uint32_t k1, uint32_t c0, uint32_t c1) {
  uint32_t ks2 = k0 ^ k1 ^ 0x1BD11BDAu;
  uint32_t x0 = c0 + k0, x1 = c1 + k1;
  const int rots[8] = {13, 15, 26, 6, 17, 29, 16, 24};
  const uint32_t ks[3] = {k0, k1, ks2};
  for (int blk = 0; blk < 5; ++blk) {
    for (int j = 0; j < 4; ++j) {
      int r = rots[(blk & 1) * 4 + j];
      x0 += x1; x1 = crotl(x1, r); x1 ^= x0;
    }
    x0 += ks[(blk + 1) % 3];
    x1 += ks[(blk + 2) % 3] + (uint32_t)(blk + 1);
  }
  return CU2{x0, x1};
}

struct Keys { uint32_t kx[D]; uint32_t ky[D]; };
constexpr Keys make_keys() {
  Keys K{};
  uint32_t a = 0u, b = 42u;  // jax.random.key(42) -> (0, 42)
  for (int i = 0; i < D; ++i) {
    CU2 sub = ctf(a, b, 0u, 1u);  // split[1] = subkey (foldlike)
    CU2 nk  = ctf(a, b, 0u, 0u);  // split[0] = carried key
    K.kx[i] = sub.a; K.ky[i] = sub.b;
    a = nk.a; b = nk.b;
  }
  return K;
}
constexpr Keys KEYS = make_keys();

// ---------------- device Threefry2x32 ---------------------------------------
__device__ __forceinline__ uint32_t rotl32(uint32_t x, int d) {
  return (x << d) | (x >> (32 - d));   // -> v_alignbit_b32
}
// keys are template params -> all key-schedule constants fold to literals
template <uint32_t K0, uint32_t K1>
__device__ __forceinline__ uint32_t tf_xor(uint32_t c1) {
  constexpr uint32_t KS2 = K0 ^ K1 ^ 0x1BD11BDAu;
  uint32_t x0 = K0, x1 = c1 + K1;      // c0 == 0 always
#define TF_RND(r) { x0 += x1; x1 = rotl32(x1, (r)); x1 ^= x0; }
  TF_RND(13) TF_RND(15) TF_RND(26) TF_RND(6)   x0 += K1;  x1 += KS2 + 1u;
  TF_RND(17) TF_RND(29) TF_RND(16) TF_RND(24)  x0 += KS2; x1 += K0 + 2u;
  TF_RND(13) TF_RND(15) TF_RND(26) TF_RND(6)   x0 += K0;  x1 += K1 + 3u;
  TF_RND(17) TF_RND(29) TF_RND(16) TF_RND(24)  x0 += K1;  x1 += KS2 + 4u;
  TF_RND(13) TF_RND(15) TF_RND(26) TF_RND(6)   x0 += KS2; x1 += K0 + 5u;
#undef TF_RND
  return x0 ^ x1;                      // bits1 ^ bits2
}

// ---------------- f32 log: Eigen/Cephes plog, Variant-E (verified R0) -------
__device__ __forceinline__ float xla_logf(float a) {
  uint32_t bits = __float_as_uint(a);
  float e = (float)((int)(bits >> 23) - 126);                    // pfrexp exp
  float m = __uint_as_float((bits & 0x007fffffu) | 0x3f000000u); // [0.5, 1)
  bool mlt = m < 0.707106781186547524f;                          // SQRTHF
  float tmp = mlt ? m : 0.0f;
  float x = __fsub_rn(m, 1.0f);
  e = __fsub_rn(e, mlt ? 1.0f : 0.0f);
  x = __fadd_rn(x, tmp);
  float x2 = __fmul_rn(x, x);
  float x3 = __fmul_rn(x2, x);
  float y  = __fmaf_rn(7.0376836292e-2f,  x, -1.1514610310e-1f);
  float y1 = __fmaf_rn(-1.2420140846e-1f, x,  1.4249322787e-1f);
  float y2 = __fmaf_rn(2.0000714765e-1f,  x, -2.4999993993e-1f);
  y  = __fmaf_rn(y,  x,  1.1676998740e-1f);
  y1 = __fmaf_rn(y1, x, -1.6668057665e-1f);
  y2 = __fmaf_rn(y2, x,  3.3333331174e-1f);
  y  = __fmaf_rn(y, x3, y1);
  y  = __fmaf_rn(y, x3, y2);
  y  = __fmul_rn(y, x3);
  y1 = __fmul_rn(e, -2.12194440e-4f);
  tmp = __fmul_rn(x2, 0.5f);
  y = __fadd_rn(y, y1);
  x = __fsub_rn(x, tmp);
  y2 = __fmul_rn(e, 0.693359375f);
  x = __fadd_rn(x, y);
  x = __fadd_rn(x, y2);
  return x;
}

__device__ __forceinline__ float gumbel_from_bits(uint32_t bits) {
  float f = __fsub_rn(__uint_as_float((bits >> 9) | 0x3f800000u), 1.0f);
  float u = __fadd_rn(f, 1.17549435e-38f);  // == f unless f == 0 -> tiny
  float l1 = xla_logf(u);
  float l2 = xla_logf(-l1);
  return -l2;
}

__device__ __forceinline__ float sgpr_f(float x) {
  return __uint_as_float(__builtin_amdgcn_readfirstlane(__float_as_uint(x)));
}

// ---------------- per-digit sampler (keys fold to literals via I) -----------
template <int I>
__device__ __forceinline__ void do_digit(const float* s_p, uint32_t n0,
                                         const int* mx, int& con, int* dg) {
  // Phase 1: 10 independent threefry streams -> reg array (ILP).
  uint32_t rb[NC];
#pragma unroll
  for (int c = 0; c < NC; ++c)
    rb[c] = tf_xor<KEYS.kx[I], KEYS.ky[I]>(n0 + (uint32_t)c);
  // Phase 2: row-uniform p into SGPRs (short live range, per digit).
  float sp[NC];
#pragma unroll
  for (int c = 0; c < NC; ++c) sp[c] = sgpr_f(s_p[I * NC + c]);
  // Phase 3: 10 independent gumbel chains + first-max scan.
  const int mxi = mx[I];
  float best = -__builtin_inff();
  int bi = 0;
#pragma unroll
  for (int c = 0; c < NC; ++c) {
    float g = gumbel_from_bits(rb[c]);
    float v = __fadd_rn(g, sp[c]);
    bool allowed = (con != 0) || (c <= mxi);
    if (allowed && v > best) { best = v; bi = c; }   // first max wins
  }
  dg[I] = bi;
  con |= (bi != mxi);
}

// ---------------- sampling kernel -------------------------------------------
// 4096 blocks x 256 threads, 1 sample/thread. 8 blocks per batch row.
__global__ __launch_bounds__(256) void sample_kernel(
    const float* __restrict__ logits,   // [B, D, NC]
    const float* __restrict__ counters, // [D, NC]
    const int*   __restrict__ s_in,     // [B]
    float* __restrict__ out,            // concat(n1_samples, n2d, weights)
    int*   __restrict__ n1buf,          // [BS] scratch (may be null)
    int    write_ws)
{
  __shared__ float s_p[D * NC];         // logit - 0.1*log(counter), this row
  const int t = threadIdx.x;
  const int blk = blockIdx.x;
  const int b = blk >> 3;               // 8 blocks per row
  if (t < D * NC) {
    s_p[t] = __fsub_rn(logits[b * D * NC + t],
                       __fmul_rn(0.1f, xla_logf(counters[t])));
  }
  __syncthreads();

  const int tid = blk * 256 + t;        // == b*S + sidx (blocks contiguous)
  const int sval = s_in[b];
  const int mx[D] = {sval / 1000, (sval / 100) % 10, (sval / 10) % 10, sval % 10};

  const uint32_t n0 = (uint32_t)tid * (uint32_t)NC;
  int con = 0;
  int dg[D];
  do_digit<0>(s_p, n0, mx, con, dg);
  do_digit<1>(s_p, n0, mx, con, dg);
  do_digit<2>(s_p, n0, mx, con, dg);
  do_digit<3>(s_p, n0, mx, con, dg);

  const int n1v = dg[0] * 1000 + dg[1] * 100 + dg[2] * 10 + dg[3];
  const int n2 = sval - n1v;            // in [0, 10^D)
  const int q0 = n2 / 1000, q1 = (n2 / 100) % 10, q2 = (n2 / 10) % 10, q3 = n2 % 10;

  const size_t o = (size_t)tid * D;
  *reinterpret_cast<float4*>(out + o) =
      make_float4((float)dg[0], (float)dg[1], (float)dg[2], (float)dg[3]);
  *reinterpret_cast<float4*>(out + OUT1_OFF + o) =
      make_float4((float)q0, (float)q1, (float)q2, (float)q3);
  if (write_ws) n1buf[tid] = n1v;
}

// ---------------- per-row multiplicity (weights) ----------------------------
// One block of 256 threads per row, 8 samples/thread, LDS histogram.
template <bool FROM_WS>
__global__ __launch_bounds__(256) void weights_kernel(
    const int* __restrict__ n1buf, float* __restrict__ out) {
  __shared__ int hist[10000];           // 40 KB -> 4 blocks/CU
  const int t = threadIdx.x;
  const int b = blockIdx.x;
  for (int i = t; i < 10000; i += 256) hist[i] = 0;
  __syncthreads();
  int vals[8];
#pragma unroll
  for (int k = 0; k < 8; ++k) {
    const int sidx = t + k * 256;
    int v;
    if (FROM_WS) {
      v = n1buf[b * S + sidx];
    } else {
      const float* p = out + ((size_t)(b * S + sidx)) * D;
      v = 1000 * (int)p[0] + 100 * (int)p[1] + 10 * (int)p[2] + (int)p[3];
    }
    vals[k] = v;
    atomicAdd(&hist[v], 1);
  }
  __syncthreads();
#pragma unroll
  for (int k = 0; k < 8; ++k) {
    const int sidx = t + k * 256;
    out[OUT2_OFF + (size_t)b * S + sidx] = (float)hist[vals[k]];
  }
}

}  // namespace

extern "C" void kernel_launch(void* const* d_in, const int* in_sizes, int n_in,
                              void* d_out, int out_size, void* d_ws, size_t ws_size,
                              hipStream_t stream) {
  const float* logits   = (const float*)d_in[0];  // [512,4,10]
  const float* counters = (const float*)d_in[1];  // [4,10]
  const int*   s_in     = (const int*)d_in[2];    // [512]
  float* out = (float*)d_out;
  int*   n1buf = (int*)d_ws;
  const int use_ws = (d_ws != nullptr && ws_size >= (size_t)BS * sizeof(int)) ? 1 : 0;

  sample_kernel<<<BS / 256, 256, 0, stream>>>(logits, counters, s_in, out,
                                              n1buf, use_ws);
  if (use_ws) weights_kernel<true><<<B, 256, 0, stream>>>(n1buf, out);
  else        weights_kernel<false><<<B, 256, 0, stream>>>(nullptr, out);
}